// Round 9
// baseline (261.594 us; speedup 1.0000x reference)
//
#include <hip/hip_runtime.h>
#include <math.h>

#define BATCH 8
#define NMEL 128
#define TT 2048
#define LL 1048576          // TT * 512
#define NCHUNK 256
#define CHUNK 4096          // LL / NCHUNK

static constexpr double RATIO  = 2047.0 / 1048575.0;   // (T-1)/(L-1)
static constexpr float  RATIOF = (float)(2047.0 / 1048575.0);
static constexpr double INV_SR = 1.0 / 44100.0;

// ---------------- weight transpose prep: w[co][m] -> wt[m][co] ----------------
__global__ __launch_bounds__(256) void wtrans_kernel(
    const float* __restrict__ w1, const float* __restrict__ w2,
    float* __restrict__ w1t, float* __restrict__ w2t)
{
    int i = blockIdx.x * 256 + threadIdx.x;
    if (i < 896 * 128) {
        int m = i >> 7, co = i & 127;
        w1t[i] = w1[co * 896 + m];
    }
    if (i < 384 * 128) {
        int m = i >> 7, co = i & 127;
        w2t[i] = w2[co * 384 + m];
    }
}

#define CONV_FMA(acc, wq, xv, K) \
    _Pragma("unroll") \
    for (int k = 0; k < K; ++k) { \
        float wv0 = wq[k].x, wv1 = wq[k].y, wv2 = wq[k].z, wv3 = wq[k].w; \
        _Pragma("unroll") \
        for (int i = 0; i < 5; ++i) { \
            acc[0][i] = fmaf(wv0, xv[i + k], acc[0][i]); \
            acc[1][i] = fmaf(wv1, xv[i + k], acc[1][i]); \
            acc[2][i] = fmaf(wv2, xv[i + k], acc[2][i]); \
            acc[3][i] = fmaf(wv3, xv[i + k], acc[3][i]); } }

// ---------------- merged: fused conv (blocks 0..511) + chunksum (512..2559) ----------------
#define XSTR 48
#define HSTR 44
__global__ __launch_bounds__(256, 3) void conv_chunk_kernel(
    const float* __restrict__ mel,   // [B][128][T]
    const float* __restrict__ w1t,   // [896][128]
    const float* __restrict__ b1,    // [128]
    const float* __restrict__ w2t,   // [384][128]
    const float* __restrict__ b2,    // [128]
    const float* __restrict__ w3,    // [2][128][3]
    const float* __restrict__ b3,    // [2]
    float* __restrict__ mags,        // [B][2][T]
    const float* __restrict__ f0f,   // [B][T]
    double* __restrict__ sums)       // [B*NCHUNK]
{
    __shared__ __align__(16) float smem[NMEL * XSTR + NMEL * HSTR]; // 47104 B
    int tid = threadIdx.x;
    int lane = tid & 63, wid = tid >> 6;

    if (blockIdx.x >= 512) {
        // ================= chunksum branch: 16 samples/thread, shared-knot ====
        int cb = blockIdx.x - 512;
        int b = cb >> 8;
        int c = cb & (NCHUNK - 1);
        const float* row = f0f + b * TT;
        int start = c * CHUNK + tid * 16;
        double pos0 = (double)start * RATIO;
        int i0s = (int)pos0;
        float wb = (float)(pos0 - (double)i0s);
        int ib = i0s + 1 > TT - 1 ? TT - 1 : i0s + 1;
        int ic = i0s + 2 > TT - 1 ? TT - 1 : i0s + 2;
        float f0a = row[i0s], f0b = row[ib], f0c = row[ic];
        double s = 0.0;
        #pragma unroll
        for (int i = 0; i < 16; ++i) {
            float wi = wb + (float)i * RATIOF;
            bool hi = wi >= 1.0f;
            float w = hi ? wi - 1.0f : wi;
            float xa = hi ? f0b : f0a, xb = hi ? f0c : f0b;
            float f0 = xa * (1.0f - w) + xb * w;
            s += (double)f0 * INV_SR;
        }
        #pragma unroll
        for (int off = 32; off > 0; off >>= 1) s += __shfl_down(s, (unsigned)off, 64);
        double* dred = (double*)smem;
        if (lane == 0) dred[wid] = s;
        __syncthreads();
        if (tid == 0) sums[cb] = dred[0] + dred[1] + dred[2] + dred[3];
        return;
    }

    // ================= conv branch =================
    float* Xs  = smem;                             // [128][48] mel, t0-8..t0+39
    float* H1  = smem + NMEL * XSTR;               // [128][44] h1, cols 0..41
    float* H2  = smem;                             // overlays Xs
    float* red = smem + NMEL * XSTR;               // overlays H1 (dead by layer 3)

    int b  = blockIdx.x >> 6;
    int t0 = (blockIdx.x & 63) * 32;
    const float* melb = mel + (size_t)b * NMEL * TT;

    // ---- stage mel: 128 rows x 12 quads (quad-aligned OOB zero-fill) ----
    #pragma unroll
    for (int it = 0; it < 6; ++it) {
        int idx = tid + it * 256;              // 0..1535
        int ci = idx / 12, q = idx - ci * 12;
        int t = t0 - 8 + q * 4;
        float4 v = make_float4(0.f, 0.f, 0.f, 0.f);
        if (t >= 0 && t + 3 < TT) v = *(const float4*)(melb + ci * TT + t);
        *(float4*)(&Xs[ci * XSTR + q * 4]) = v;
    }
    if (tid < 128) { H1[tid * HSTR + 0] = 0.f; H1[tid * HSTR + 41] = 0.f; }
    __syncthreads();

    int cog = tid >> 3;                        // 0..31 -> co = cog*4+j
    int tg  = tid & 7;                         // 0..7
    int xbase = 1 + tg * 5;

    // ---- layer 1 (K=7): ping-pong pipelined; h1 cols 1..40 ----
    {
        float acc[4][5];
        #pragma unroll
        for (int j = 0; j < 4; ++j) {
            float bj = b1[cog * 4 + j];
            #pragma unroll
            for (int i = 0; i < 5; ++i) acc[j][i] = bj;
        }
        const float* wb_ = w1t + cog * 4;
        float xvA[11], xvB[11];
        float4 wA[7], wB[7];
        #pragma unroll
        for (int i = 0; i < 11; ++i) xvA[i] = Xs[xbase + i];
        #pragma unroll
        for (int k = 0; k < 7; ++k) wA[k] = *(const float4*)(wb_ + (size_t)k * 128);
        for (int ci = 0; ci < NMEL; ci += 2) {
            int c1 = ci + 1;
            #pragma unroll
            for (int i = 0; i < 11; ++i) xvB[i] = Xs[c1 * XSTR + xbase + i];
            #pragma unroll
            for (int k = 0; k < 7; ++k) wB[k] = *(const float4*)(wb_ + (size_t)(c1 * 7 + k) * 128);
            CONV_FMA(acc, wA, xvA, 7)
            int c2 = ci + 2 < NMEL ? ci + 2 : NMEL - 1;
            #pragma unroll
            for (int i = 0; i < 11; ++i) xvA[i] = Xs[c2 * XSTR + xbase + i];
            #pragma unroll
            for (int k = 0; k < 7; ++k) wA[k] = *(const float4*)(wb_ + (size_t)(c2 * 7 + k) * 128);
            CONV_FMA(acc, wB, xvB, 7)
        }
        #pragma unroll
        for (int j = 0; j < 4; ++j)
            #pragma unroll
            for (int i = 0; i < 5; ++i) {
                int t = t0 - 4 + tg * 5 + i;
                float v = acc[j][i];
                v = v > 0.0f ? v : 0.2f * v;
                if (t < 0 || t >= TT) v = 0.0f;       // conv2 zero-padding
                H1[(cog * 4 + j) * HSTR + 1 + tg * 5 + i] = v;
            }
    }
    __syncthreads();

    // ---- layer 2 (K=3): pipelined; h2 cols 0..39, H2 overlays Xs ----
    {
        float acc[4][5];
        #pragma unroll
        for (int j = 0; j < 4; ++j) {
            float bj = b2[cog * 4 + j];
            #pragma unroll
            for (int i = 0; i < 5; ++i) acc[j][i] = bj;
        }
        int hbase = tg * 5;
        const float* wb_ = w2t + cog * 4;
        float xvA[7], xvB[7];
        float4 wA[3], wB[3];
        #pragma unroll
        for (int i = 0; i < 7; ++i) xvA[i] = H1[hbase + i];
        #pragma unroll
        for (int k = 0; k < 3; ++k) wA[k] = *(const float4*)(wb_ + (size_t)k * 128);
        for (int ci = 0; ci < NMEL; ci += 2) {
            int c1 = ci + 1;
            #pragma unroll
            for (int i = 0; i < 7; ++i) xvB[i] = H1[c1 * HSTR + hbase + i];
            #pragma unroll
            for (int k = 0; k < 3; ++k) wB[k] = *(const float4*)(wb_ + (size_t)(c1 * 3 + k) * 128);
            CONV_FMA(acc, wA, xvA, 3)
            int c2 = ci + 2 < NMEL ? ci + 2 : NMEL - 1;
            #pragma unroll
            for (int i = 0; i < 7; ++i) xvA[i] = H1[c2 * HSTR + hbase + i];
            #pragma unroll
            for (int k = 0; k < 3; ++k) wA[k] = *(const float4*)(wb_ + (size_t)(c2 * 3 + k) * 128);
            CONV_FMA(acc, wB, xvB, 3)
        }
        #pragma unroll
        for (int j = 0; j < 4; ++j)
            #pragma unroll
            for (int i = 0; i < 5; ++i) {
                int t = t0 - 4 + tg * 5 + i;
                float v = acc[j][i];
                v = v > 0.0f ? v : 0.2f * v;
                if (t < 0 || t >= TT) v = 0.0f;       // conv3 zero-padding
                H2[(cog * 4 + j) * HSTR + tg * 5 + i] = v;
            }
    }
    __syncthreads();

    // ---- layer 3 (128 -> 2, K=3, clip [0,1]) ----
    {
        int o   = tid >> 7;
        int cig = (tid >> 5) & 3;
        int tt  = tid & 31;
        float a = 0.0f;
        for (int cl = 0; cl < 32; ++cl) {
            int ci = cig * 32 + cl;
            #pragma unroll
            for (int k = 0; k < 3; ++k)
                a = fmaf(w3[o * 384 + ci * 3 + k], H2[ci * HSTR + tt + 3 + k], a);
        }
        red[(o * 4 + cig) * 32 + tt] = a;
    }
    __syncthreads();
    if (tid < 64) {
        int o = tid >> 5, tt = tid & 31;
        float s = b3[o] + red[(o * 4 + 0) * 32 + tt] + red[(o * 4 + 1) * 32 + tt]
                        + red[(o * 4 + 2) * 32 + tt] + red[(o * 4 + 3) * 32 + tt];
        s = fminf(fmaxf(s, 0.0f), 1.0f);
        mags[((size_t)b * 2 + o) * TT + t0 + tt] = s;
    }
}

// ---------------- final fused kernel (includes per-block prefix of sums) ----------------
__device__ __forceinline__ int swz4(int g) { return g ^ ((g >> 3) & 7); }

__global__ __launch_bounds__(256, 4) void final_kernel(
    const float* __restrict__ f0f,
    const float* __restrict__ noise,
    const float* __restrict__ mags,
    const double* __restrict__ sums,
    float* __restrict__ out)
{
    int b = blockIdx.x >> 8;
    int c = blockIdx.x & (NCHUNK - 1);
    const float* row = f0f + b * TT;
    int tid = threadIdx.x;
    int lane = tid & 63, wid = tid >> 6;
    __shared__ float4 fracsV[CHUNK / 4];       // 16 KB
    __shared__ double wsumP[4], wsumA[4];

    int chunkBase = c * CHUNK;
    int start = chunkBase + tid * 16;

    // ---- chunk-offset partial: sum of sums[b][c'<c] ----
    double part = (tid < c) ? sums[b * NCHUNK + tid] : 0.0;
    #pragma unroll
    for (int off = 32; off > 0; off >>= 1) part += __shfl_down(part, (unsigned)off, 64);
    if (lane == 0) wsumP[wid] = part;

    // ---- phase A: 16 samples/thread, shared-knot f0, f64 cumsum ----
    double pos0 = (double)start * RATIO;
    int i0s = (int)pos0;
    float wb = (float)(pos0 - (double)i0s);
    int ibk = i0s + 1 > TT - 1 ? TT - 1 : i0s + 1;
    int ick = i0s + 2 > TT - 1 ? TT - 1 : i0s + 2;
    float f0a = row[i0s], f0b = row[ibk], f0c = row[ick];
    float f0v[16];
    double s = 0.0;
    #pragma unroll
    for (int i = 0; i < 16; ++i) {
        float wi = wb + (float)i * RATIOF;
        bool hi = wi >= 1.0f;
        float w = hi ? wi - 1.0f : wi;
        float xa = hi ? f0b : f0a, xb = hi ? f0c : f0b;
        f0v[i] = xa * (1.0f - w) + xb * w;
        s += (double)f0v[i] * INV_SR;
    }
    double incl = s;
    #pragma unroll
    for (int off = 1; off < 64; off <<= 1) {
        double v = __shfl_up(incl, (unsigned)off, 64);
        if (lane >= off) incl += v;
    }
    if (lane == 63) wsumA[wid] = incl;
    __syncthreads();
    double run = wsumP[0] + wsumP[1] + wsumP[2] + wsumP[3] + (incl - s);
    for (int w = 0; w < wid; ++w) run += wsumA[w];

    // ---- emit phase fractions as swizzled float4 groups ----
    float fb[4];
    #pragma unroll
    for (int i = 0; i < 16; ++i) {
        run += (double)f0v[i] * INV_SR;
        double fr = run - rint(run);               // phase - round(phase)
        fb[i & 3] = (float)fr;
        if ((i & 3) == 3)
            fracsV[swz4(tid * 4 + (i >> 2))] = make_float4(fb[0], fb[1], fb[2], fb[3]);
    }
    __syncthreads();

    const size_t BL = (size_t)BATCH * LL;
    const size_t outBase = (size_t)b * LL;
    const float* m0row = mags + (size_t)b * 2 * TT;
    const float* m1row = m0row + TT;

    #pragma unroll
    for (int g = 0; g < 4; ++g) {
        int G = g * 256 + tid;
        int n0 = chunkBase + G * 4;
        float4 fr4 = fracsV[swz4(G)];
        const float* frp = (const float*)&fr4;
        float4 nz4 = *(const float4*)(noise + outBase + n0);
        const float* nzp = (const float*)&nz4;

        double posg = (double)n0 * RATIO;
        int i0a = (int)posg;
        float wf = (float)(posg - (double)i0a);
        int ib = i0a + 1 > TT - 1 ? TT - 1 : i0a + 1;
        int ic = i0a + 2 > TT - 1 ? TT - 1 : i0a + 2;
        float g0a = row[i0a],   g0b = row[ib],   g0c = row[ic];
        float m0a = m0row[i0a], m0b = m0row[ib], m0c = m0row[ic];
        float m1a = m1row[i0a], m1b = m1row[ib], m1c = m1row[ic];

        float so[4], co_[4], no_[4];
        #pragma unroll
        for (int j = 0; j < 4; ++j) {
            float wj = wf + (float)j * RATIOF;
            bool hi = wj >= 1.0f;
            float w = hi ? wj - 1.0f : wj;
            float xa = hi ? g0b : g0a, xb = hi ? g0c : g0b;
            float f0 = xa * (1.0f - w) + xb * w;
            float ya = hi ? m0b : m0a, yb = hi ? m0c : m0b;
            float m0 = ya * (1.0f - w) + yb * w;
            float za = hi ? m1b : m1a, zb = hi ? m1c : m1b;
            float m1 = za * (1.0f - w) + zb * w;

            float ph = frp[j];
            float x  = 44100.0f * ph * __builtin_amdgcn_rcpf(f0 + 1e-8f);
            float px = 3.14159265358979323f * x;
            float rr = 0.5f * x;
            float rf = rr - rintf(rr);             // exact reduction to revolutions
            float sn;
            asm("v_sin_f32 %0, %1" : "=v"(sn) : "v"(rf));
            float comb = (x == 0.0f) ? 1.0f : sn * __builtin_amdgcn_rcpf(px);

            float ns = fminf(fmaxf(nzp[j] * m0, -1.0f), 1.0f);
            float cs = fminf(fmaxf(comb * m1, -1.0f), 1.0f);
            so[j] = fminf(fmaxf(ns + cs, -1.0f), 1.0f);
            co_[j] = cs; no_[j] = ns;
        }
        *(float4*)(out + outBase + n0)          = make_float4(so[0], so[1], so[2], so[3]);
        *(float4*)(out + BL + outBase + n0)     = make_float4(co_[0], co_[1], co_[2], co_[3]);
        *(float4*)(out + 2 * BL + outBase + n0) = make_float4(no_[0], no_[1], no_[2], no_[3]);
    }
}

extern "C" void kernel_launch(void* const* d_in, const int* in_sizes, int n_in,
                              void* d_out, int out_size, void* d_ws, size_t ws_size,
                              hipStream_t stream) {
    const float* mel   = (const float*)d_in[0];  // [8,128,2048]
    const float* f0f   = (const float*)d_in[1];  // [8,2048]
    const float* noise = (const float*)d_in[2];  // [8,1048576]
    const float* w1    = (const float*)d_in[3];  // [128,128,7]
    const float* b1    = (const float*)d_in[4];
    const float* w2    = (const float*)d_in[5];  // [128,128,3]
    const float* b2    = (const float*)d_in[6];
    const float* w3    = (const float*)d_in[7];  // [2,128,3]
    const float* b3    = (const float*)d_in[8];
    float* out = (float*)d_out;

    // workspace layout
    float* w1t  = (float*)d_ws;                      // 896*128
    float* w2t  = w1t + 896 * 128;                   // 384*128
    float* mags = w2t + 384 * 128;                   // 8*2*2048
    double* sums = (double*)(mags + BATCH * 2 * TT); // 8B-aligned, B*NCHUNK doubles

    wtrans_kernel<<<(896 * 128 + 255) / 256, 256, 0, stream>>>(w1, w2, w1t, w2t);
    conv_chunk_kernel<<<512 + BATCH * NCHUNK, 256, 0, stream>>>(
        mel, w1t, b1, w2t, b2, w3, b3, mags, f0f, sums);
    final_kernel<<<BATCH * NCHUNK, 256, 0, stream>>>(f0f, noise, mags, sums, out);
}